// Round 1
// baseline (873.605 us; speedup 1.0000x reference)
//
#include <hip/hip_runtime.h>

#define N_NODES 32768
#define EMBED   512
#define NNZ_TOT 1048576
#define LN_EPS  1e-5f

// ---------------- zero scratch ints ----------------
__global__ void zero_ints(int* __restrict__ p, int n) {
    int i = blockIdx.x * blockDim.x + threadIdx.x;
    if (i < n) p[i] = 0;
}

// ---------------- gather + GEMM: support = emb[uids] @ W ----------------
// fp32 tiled GEMM, BM=BN=64, BK=16, 256 threads, 4x4 microtile per thread.
#define BM 64
#define BN 64
#define BK 16
__global__ __launch_bounds__(256) void gemm_gather(
    const int* __restrict__ uids, const float* __restrict__ emb,
    const float* __restrict__ W, float* __restrict__ support)
{
    __shared__ float As[BK][BM + 4];   // +4 pad keeps rows 16B-aligned, 2-way banks only
    __shared__ float Bs[BK][BN];

    const int t  = threadIdx.x;
    const int n0 = blockIdx.x * BN;
    const int m0 = blockIdx.y * BM;

    // A-load mapping: each thread loads one float4 of one gathered row
    const int ar = t >> 2;            // 0..63 row within tile
    const int kc = (t & 3) * 4;       // 0,4,8,12 col offset within K-chunk
    const int uid = uids[m0 + ar];
    const float* abase = emb + (long)uid * EMBED;

    // B-load mapping
    const int bkr = t >> 4;           // 0..15
    const int bc  = (t & 15) * 4;

    // compute mapping
    const int ty = t >> 4;            // 0..15 -> 4 rows each
    const int tx = t & 15;            // 0..15 -> 4 cols each

    float acc[4][4] = {};

    for (int k0 = 0; k0 < EMBED; k0 += BK) {
        float4 av = *(const float4*)(abase + k0 + kc);
        float4 bv = *(const float4*)(W + (long)(k0 + bkr) * EMBED + n0 + bc);
        As[kc + 0][ar] = av.x;
        As[kc + 1][ar] = av.y;
        As[kc + 2][ar] = av.z;
        As[kc + 3][ar] = av.w;
        *(float4*)&Bs[bkr][bc] = bv;
        __syncthreads();
#pragma unroll
        for (int kk = 0; kk < BK; ++kk) {
            float4 a = *(const float4*)&As[kk][ty * 4];
            float4 b = *(const float4*)&Bs[kk][tx * 4];
            acc[0][0] = fmaf(a.x, b.x, acc[0][0]);
            acc[0][1] = fmaf(a.x, b.y, acc[0][1]);
            acc[0][2] = fmaf(a.x, b.z, acc[0][2]);
            acc[0][3] = fmaf(a.x, b.w, acc[0][3]);
            acc[1][0] = fmaf(a.y, b.x, acc[1][0]);
            acc[1][1] = fmaf(a.y, b.y, acc[1][1]);
            acc[1][2] = fmaf(a.y, b.z, acc[1][2]);
            acc[1][3] = fmaf(a.y, b.w, acc[1][3]);
            acc[2][0] = fmaf(a.z, b.x, acc[2][0]);
            acc[2][1] = fmaf(a.z, b.y, acc[2][1]);
            acc[2][2] = fmaf(a.z, b.z, acc[2][2]);
            acc[2][3] = fmaf(a.z, b.w, acc[2][3]);
            acc[3][0] = fmaf(a.w, b.x, acc[3][0]);
            acc[3][1] = fmaf(a.w, b.y, acc[3][1]);
            acc[3][2] = fmaf(a.w, b.z, acc[3][2]);
            acc[3][3] = fmaf(a.w, b.w, acc[3][3]);
        }
        __syncthreads();
    }

#pragma unroll
    for (int i = 0; i < 4; ++i) {
        float4 o = make_float4(acc[i][0], acc[i][1], acc[i][2], acc[i][3]);
        *(float4*)&support[(long)(m0 + ty * 4 + i) * EMBED + n0 + tx * 4] = o;
    }
}

// ---------------- CSR build ----------------
__global__ void hist_kernel(const int* __restrict__ adj_row, int* __restrict__ counts) {
    int i = blockIdx.x * blockDim.x + threadIdx.x;
    if (i < NNZ_TOT) atomicAdd(&counts[adj_row[i]], 1);
}

__global__ __launch_bounds__(1024) void scan_kernel(
    const int* __restrict__ counts, int* __restrict__ row_start)
{
    __shared__ int ssum[1024];
    const int t = threadIdx.x;
    const int base = t * 32;
    int loc[32];
    int run = 0;
#pragma unroll
    for (int i = 0; i < 32; ++i) {
        int c = counts[base + i];
        loc[i] = run;
        run += c;
    }
    ssum[t] = run;
    __syncthreads();
    for (int off = 1; off < 1024; off <<= 1) {
        int v = (t >= off) ? ssum[t - off] : 0;
        __syncthreads();
        ssum[t] += v;
        __syncthreads();
    }
    int prefix = (t > 0) ? ssum[t - 1] : 0;
#pragma unroll
    for (int i = 0; i < 32; ++i) row_start[base + i] = prefix + loc[i];
    if (t == 1023) row_start[N_NODES] = ssum[1023];
}

__global__ void scatter_kernel(
    const int* __restrict__ adj_row, const int* __restrict__ adj_col,
    const float* __restrict__ adj_vals, const int* __restrict__ row_start,
    int* __restrict__ cursor, int* __restrict__ sc_col, float* __restrict__ sc_val)
{
    int i = blockIdx.x * blockDim.x + threadIdx.x;
    if (i < NNZ_TOT) {
        int r = adj_row[i];
        int pos = atomicAdd(&cursor[r], 1);
        int o = row_start[r] + pos;
        sc_col[o] = adj_col[i];
        sc_val[o] = adj_vals[i];
    }
}

// ---------------- aggregation + bias + LayerNorm ----------------
__global__ __launch_bounds__(256) void agg_ln_kernel(
    const int* __restrict__ row_start, const int* __restrict__ sc_col,
    const float* __restrict__ sc_val, const float* __restrict__ support,
    const float* __restrict__ bias, const float* __restrict__ gamma,
    const float* __restrict__ beta, float* __restrict__ out)
{
    const int n = blockIdx.x;
    const int t = threadIdx.x;
    const int s = row_start[n];
    const int e = row_start[n + 1];

    float a0 = 0.f, a1 = 0.f;
    for (int i = s; i < e; ++i) {
        int c = sc_col[i];
        float v = sc_val[i];
        const float* sp = support + (long)c * EMBED;
        a0 = fmaf(v, sp[t], a0);
        a1 = fmaf(v, sp[t + 256], a1);
    }
    float x0 = a0 + bias[t];
    float x1 = a1 + bias[t + 256];

    // block reduction for sum and sum-of-squares over 512 values
    float s1 = x0 + x1;
    float s2 = x0 * x0 + x1 * x1;
#pragma unroll
    for (int off = 32; off > 0; off >>= 1) {
        s1 += __shfl_down(s1, off, 64);
        s2 += __shfl_down(s2, off, 64);
    }
    __shared__ float ws1[4], ws2[4];
    const int wid = t >> 6, lane = t & 63;
    if (lane == 0) { ws1[wid] = s1; ws2[wid] = s2; }
    __syncthreads();
    if (t == 0) {
        float S = ws1[0] + ws1[1] + ws1[2] + ws1[3];
        float Q = ws2[0] + ws2[1] + ws2[2] + ws2[3];
        ws1[0] = S;
        ws2[0] = Q;
    }
    __syncthreads();
    const float mean = ws1[0] * (1.f / 512.f);
    const float var  = ws2[0] * (1.f / 512.f) - mean * mean;
    const float rstd = rsqrtf(var + LN_EPS);

    out[(long)n * EMBED + t]       = (x0 - mean) * rstd * gamma[t] + beta[t];
    out[(long)n * EMBED + t + 256] = (x1 - mean) * rstd * gamma[t + 256] + beta[t + 256];
}

// ---------------- launch ----------------
extern "C" void kernel_launch(void* const* d_in, const int* in_sizes, int n_in,
                              void* d_out, int out_size, void* d_ws, size_t ws_size,
                              hipStream_t stream)
{
    const int*   user_ids = (const int*)  d_in[0];   // [16,2048]
    const int*   adj_row  = (const int*)  d_in[1];   // [NNZ]
    const int*   adj_col  = (const int*)  d_in[2];   // [NNZ]
    const float* adj_vals = (const float*)d_in[3];   // [NNZ]
    const float* emb      = (const float*)d_in[4];   // [100000,512]
    const float* W        = (const float*)d_in[5];   // [512,512]
    const float* bias     = (const float*)d_in[6];   // [512]
    const float* gamma    = (const float*)d_in[7];   // [512]
    const float* beta     = (const float*)d_in[8];   // [512]
    float* out = (float*)d_out;

    char* ws = (char*)d_ws;
    size_t off = 0;
    float* support  = (float*)(ws + off); off += (size_t)N_NODES * EMBED * 4;  // 64 MB
    int*   row_start= (int*)  (ws + off); off += (size_t)(N_NODES + 4) * 4;
    int*   counts   = (int*)  (ws + off); off += (size_t)N_NODES * 4;
    int*   cursor   = (int*)  (ws + off); off += (size_t)N_NODES * 4;          // contiguous w/ counts
    int*   sc_col   = (int*)  (ws + off); off += (size_t)NNZ_TOT * 4;
    float* sc_val   = (float*)(ws + off); off += (size_t)NNZ_TOT * 4;
    (void)off; (void)ws_size; (void)in_sizes; (void)n_in; (void)out_size;

    // counts and cursor are NOT contiguous (row_start sits between support and counts,
    // but counts/cursor are adjacent) -> zero both in one pass
    zero_ints<<<(2 * N_NODES + 255) / 256, 256, 0, stream>>>(counts, 2 * N_NODES);

    gemm_gather<<<dim3(EMBED / BN, N_NODES / BM), 256, 0, stream>>>(user_ids, emb, W, support);

    hist_kernel<<<NNZ_TOT / 256, 256, 0, stream>>>(adj_row, counts);
    scan_kernel<<<1, 1024, 0, stream>>>(counts, row_start);
    scatter_kernel<<<NNZ_TOT / 256, 256, 0, stream>>>(adj_row, adj_col, adj_vals,
                                                      row_start, cursor, sc_col, sc_val);

    agg_ln_kernel<<<N_NODES, 256, 0, stream>>>(row_start, sc_col, sc_val, support,
                                               bias, gamma, beta, out);
}

// Round 2
// 655.554 us; speedup vs baseline: 1.3326x; 1.3326x over previous
//
#include <hip/hip_runtime.h>

#define N_NODES 32768
#define EMBED   512
#define NNZ_TOT 1048576
#define LN_EPS  1e-5f

typedef __attribute__((ext_vector_type(8))) short bf16x8;
typedef __attribute__((ext_vector_type(4))) float f32x4;
typedef __attribute__((ext_vector_type(4))) unsigned int u32x4;

__device__ __forceinline__ unsigned short f2bf(float x) {
    unsigned int u = __float_as_uint(x);
    unsigned int r = u + 0x7fffu + ((u >> 16) & 1u);   // RNE
    return (unsigned short)(r >> 16);
}
__device__ __forceinline__ unsigned int pk2(float a, float b) {
    return (unsigned int)f2bf(a) | ((unsigned int)f2bf(b) << 16);
}

// ---------------- zero scratch ints ----------------
__global__ void zero_ints(int* __restrict__ p, int n) {
    int i = blockIdx.x * blockDim.x + threadIdx.x;
    if (i < n) p[i] = 0;
}

// ---------------- W [k][n] fp32 -> Wt [n][k] bf16 ----------------
__global__ __launch_bounds__(256) void wt_kernel(
    const float* __restrict__ W, unsigned short* __restrict__ Wt)
{
    __shared__ float tile[32][33];
    const int tx = threadIdx.x & 31, ty = threadIdx.x >> 5;  // ty 0..7
    const int kb = blockIdx.y * 32, nb = blockIdx.x * 32;
#pragma unroll
    for (int i = 0; i < 32; i += 8)
        tile[ty + i][tx] = W[(long)(kb + ty + i) * EMBED + nb + tx];
    __syncthreads();
#pragma unroll
    for (int i = 0; i < 32; i += 8)
        Wt[(long)(nb + ty + i) * EMBED + kb + tx] = f2bf(tile[tx][ty + i]);
}

// ---------------- gather + bf16 MFMA GEMM: support = bf16(emb[uids]) @ bf16(W) ----------------
// 128x128 block tile, BK=32, 256 threads = 4 waves in 2x2, each wave 64x64 (4x4 mfma 16x16x32).
__global__ __launch_bounds__(256) void gemm_mfma(
    const int* __restrict__ uids, const float* __restrict__ emb,
    const unsigned short* __restrict__ Wt, unsigned short* __restrict__ support)
{
    // row stride 40 ushorts = 80 B -> frag reads land on 2-way bank aliasing only (free)
    __shared__ unsigned short As[128][40];
    __shared__ unsigned short Bs[128][40];

    const int t  = threadIdx.x;
    const int m0 = blockIdx.y * 128;
    const int n0 = blockIdx.x * 128;

    const int wave = t >> 6;
    const int lane = t & 63;
    const int wm   = (wave & 1) * 64;
    const int wn   = (wave >> 1) * 64;
    const int l16  = lane & 15;
    const int quad = lane >> 4;

    // staging mapping: thread -> (row 0..127, k-half 0/16)
    const int srow  = t >> 1;
    const int shalf = (t & 1) * 16;
    const int uid   = uids[m0 + srow];
    const float* arow = emb + (long)uid * EMBED + shalf;
    const unsigned short* brow = Wt + (long)(n0 + srow) * EMBED + shalf;

    f32x4 acc[4][4] = {};

    for (int k0 = 0; k0 < EMBED; k0 += 32) {
        // A: 16 fp32 -> 16 bf16
        const float4* ap = (const float4*)(arow + k0);
        float4 v0 = ap[0], v1 = ap[1], v2 = ap[2], v3 = ap[3];
        u32x4 lo, hi;
        lo.x = pk2(v0.x, v0.y); lo.y = pk2(v0.z, v0.w);
        lo.z = pk2(v1.x, v1.y); lo.w = pk2(v1.z, v1.w);
        hi.x = pk2(v2.x, v2.y); hi.y = pk2(v2.z, v2.w);
        hi.z = pk2(v3.x, v3.y); hi.w = pk2(v3.z, v3.w);
        *(u32x4*)&As[srow][shalf]     = lo;
        *(u32x4*)&As[srow][shalf + 8] = hi;
        // B: already bf16, straight copy 32 B
        const u32x4* bp = (const u32x4*)(brow + k0);
        *(u32x4*)&Bs[srow][shalf]     = bp[0];
        *(u32x4*)&Bs[srow][shalf + 8] = bp[1];
        __syncthreads();

        bf16x8 af[4], bf[4];
#pragma unroll
        for (int i = 0; i < 4; ++i)
            af[i] = *(const bf16x8*)&As[wm + i * 16 + l16][quad * 8];
#pragma unroll
        for (int j = 0; j < 4; ++j)
            bf[j] = *(const bf16x8*)&Bs[wn + j * 16 + l16][quad * 8];
#pragma unroll
        for (int i = 0; i < 4; ++i)
#pragma unroll
            for (int j = 0; j < 4; ++j)
                acc[i][j] = __builtin_amdgcn_mfma_f32_16x16x32_bf16(af[i], bf[j], acc[i][j], 0, 0, 0);
        __syncthreads();
    }

    // epilogue: C/D layout col=lane&15, row=quad*4+reg
#pragma unroll
    for (int i = 0; i < 4; ++i) {
#pragma unroll
        for (int j = 0; j < 4; ++j) {
            const int col = n0 + wn + j * 16 + l16;
#pragma unroll
            for (int r = 0; r < 4; ++r) {
                const int row = m0 + wm + i * 16 + quad * 4 + r;
                support[(long)row * EMBED + col] = f2bf(acc[i][j][r]);
            }
        }
    }
}

// ---------------- CSR build ----------------
__global__ void hist_kernel(const int* __restrict__ adj_row, int* __restrict__ counts) {
    int i = blockIdx.x * blockDim.x + threadIdx.x;
    if (i < NNZ_TOT) atomicAdd(&counts[adj_row[i]], 1);
}

__global__ __launch_bounds__(1024) void scan_kernel(
    const int* __restrict__ counts, int* __restrict__ row_start)
{
    __shared__ int ssum[1024];
    const int t = threadIdx.x;
    const int base = t * 32;
    int loc[32];
    int run = 0;
#pragma unroll
    for (int i = 0; i < 32; ++i) {
        int c = counts[base + i];
        loc[i] = run;
        run += c;
    }
    ssum[t] = run;
    __syncthreads();
    for (int off = 1; off < 1024; off <<= 1) {
        int v = (t >= off) ? ssum[t - off] : 0;
        __syncthreads();
        ssum[t] += v;
        __syncthreads();
    }
    int prefix = (t > 0) ? ssum[t - 1] : 0;
#pragma unroll
    for (int i = 0; i < 32; ++i) row_start[base + i] = prefix + loc[i];
    if (t == 1023) row_start[N_NODES] = ssum[1023];
}

__global__ void scatter_kernel(
    const int* __restrict__ adj_row, const int* __restrict__ adj_col,
    const float* __restrict__ adj_vals, const int* __restrict__ row_start,
    int* __restrict__ cursor, int* __restrict__ sc_col, float* __restrict__ sc_val)
{
    int i = blockIdx.x * blockDim.x + threadIdx.x;
    if (i < NNZ_TOT) {
        int r = adj_row[i];
        int pos = atomicAdd(&cursor[r], 1);
        int o = row_start[r] + pos;
        sc_col[o] = adj_col[i];
        sc_val[o] = adj_vals[i];
    }
}

// ---------------- aggregation (bf16 support) + bias + LayerNorm ----------------
__global__ __launch_bounds__(256) void agg_ln_bf16(
    const int* __restrict__ row_start, const int* __restrict__ sc_col,
    const float* __restrict__ sc_val, const unsigned short* __restrict__ support,
    const float* __restrict__ bias, const float* __restrict__ gamma,
    const float* __restrict__ beta, float* __restrict__ out)
{
    const int n = blockIdx.x;
    const int t = threadIdx.x;
    const int s = row_start[n];
    const int e = row_start[n + 1];
    const int d = t * 2;             // this thread owns dims d, d+1

    float a0 = 0.f, a1 = 0.f;
    for (int i = s; i < e; ++i) {
        int c = sc_col[i];
        float v = sc_val[i];
        unsigned int u = *(const unsigned int*)(support + (long)c * EMBED + d);
        float f0 = __uint_as_float(u << 16);
        float f1 = __uint_as_float(u & 0xffff0000u);
        a0 = fmaf(v, f0, a0);
        a1 = fmaf(v, f1, a1);
    }
    float x0 = a0 + bias[d];
    float x1 = a1 + bias[d + 1];

    float s1 = x0 + x1;
    float s2 = x0 * x0 + x1 * x1;
#pragma unroll
    for (int off = 32; off > 0; off >>= 1) {
        s1 += __shfl_down(s1, off, 64);
        s2 += __shfl_down(s2, off, 64);
    }
    __shared__ float ws1[4], ws2[4];
    const int wid = t >> 6, lane = t & 63;
    if (lane == 0) { ws1[wid] = s1; ws2[wid] = s2; }
    __syncthreads();
    if (t == 0) {
        ws1[0] = ws1[0] + ws1[1] + ws1[2] + ws1[3];
        ws2[0] = ws2[0] + ws2[1] + ws2[2] + ws2[3];
    }
    __syncthreads();
    const float mean = ws1[0] * (1.f / 512.f);
    const float var  = ws2[0] * (1.f / 512.f) - mean * mean;
    const float rstd = rsqrtf(var + LN_EPS);

    float2 o;
    o.x = (x0 - mean) * rstd * gamma[d] + beta[d];
    o.y = (x1 - mean) * rstd * gamma[d + 1] + beta[d + 1];
    *(float2*)&out[(long)n * EMBED + d] = o;
}

// ---------------- launch ----------------
extern "C" void kernel_launch(void* const* d_in, const int* in_sizes, int n_in,
                              void* d_out, int out_size, void* d_ws, size_t ws_size,
                              hipStream_t stream)
{
    const int*   user_ids = (const int*)  d_in[0];
    const int*   adj_row  = (const int*)  d_in[1];
    const int*   adj_col  = (const int*)  d_in[2];
    const float* adj_vals = (const float*)d_in[3];
    const float* emb      = (const float*)d_in[4];
    const float* W        = (const float*)d_in[5];
    const float* bias     = (const float*)d_in[6];
    const float* gamma    = (const float*)d_in[7];
    const float* beta     = (const float*)d_in[8];
    float* out = (float*)d_out;

    char* ws = (char*)d_ws;
    size_t off = 0;
    unsigned short* support = (unsigned short*)(ws + off); off += (size_t)N_NODES * EMBED * 2; // 32 MB
    unsigned short* Wt      = (unsigned short*)(ws + off); off += (size_t)EMBED * EMBED * 2;   // 512 KB
    int*   row_start = (int*)  (ws + off); off += (size_t)(N_NODES + 4) * 4;
    int*   counts    = (int*)  (ws + off); off += (size_t)N_NODES * 4;
    int*   cursor    = (int*)  (ws + off); off += (size_t)N_NODES * 4;   // contiguous with counts
    int*   sc_col    = (int*)  (ws + off); off += (size_t)NNZ_TOT * 4;
    float* sc_val    = (float*)(ws + off); off += (size_t)NNZ_TOT * 4;
    (void)off; (void)ws_size; (void)in_sizes; (void)n_in; (void)out_size;

    zero_ints<<<(2 * N_NODES + 255) / 256, 256, 0, stream>>>(counts, 2 * N_NODES);

    wt_kernel<<<dim3(16, 16), 256, 0, stream>>>(W, Wt);

    gemm_mfma<<<dim3(EMBED / 128, N_NODES / 128), 256, 0, stream>>>(user_ids, emb, Wt, support);

    hist_kernel<<<NNZ_TOT / 256, 256, 0, stream>>>(adj_row, counts);
    scan_kernel<<<1, 1024, 0, stream>>>(counts, row_start);
    scatter_kernel<<<NNZ_TOT / 256, 256, 0, stream>>>(adj_row, adj_col, adj_vals,
                                                      row_start, cursor, sc_col, sc_val);

    agg_ln_bf16<<<N_NODES, 256, 0, stream>>>(row_start, sc_col, sc_val, support,
                                             bias, gamma, beta, out);
}

// Round 3
// 553.852 us; speedup vs baseline: 1.5773x; 1.1836x over previous
//
#include <hip/hip_runtime.h>

#define N_NODES 32768
#define EMBED   512
#define NNZ_TOT 1048576
#define LN_EPS  1e-5f

typedef __attribute__((ext_vector_type(8))) short bf16x8;
typedef __attribute__((ext_vector_type(4))) float f32x4;
typedef __attribute__((ext_vector_type(4))) unsigned int u32x4;

__device__ __forceinline__ unsigned short f2bf(float x) {
    unsigned int u = __float_as_uint(x);
    unsigned int r = u + 0x7fffu + ((u >> 16) & 1u);   // RNE
    return (unsigned short)(r >> 16);
}
__device__ __forceinline__ unsigned int pk2(float a, float b) {
    return (unsigned int)f2bf(a) | ((unsigned int)f2bf(b) << 16);
}

// ---------------- zero scratch ints ----------------
__global__ void zero_ints(int* __restrict__ p, int n) {
    int i = blockIdx.x * blockDim.x + threadIdx.x;
    if (i < n) p[i] = 0;
}

// ---------------- W [k][n] fp32 -> Wt [n][k] bf16 ----------------
__global__ __launch_bounds__(256) void wt_kernel(
    const float* __restrict__ W, unsigned short* __restrict__ Wt)
{
    __shared__ float tile[32][33];
    const int tx = threadIdx.x & 31, ty = threadIdx.x >> 5;  // ty 0..7
    const int kb = blockIdx.y * 32, nb = blockIdx.x * 32;
#pragma unroll
    for (int i = 0; i < 32; i += 8)
        tile[ty + i][tx] = W[(long)(kb + ty + i) * EMBED + nb + tx];
    __syncthreads();
#pragma unroll
    for (int i = 0; i < 32; i += 8)
        Wt[(long)(nb + ty + i) * EMBED + kb + tx] = f2bf(tile[tx][ty + i]);
}

// ---------------- gather + bf16 MFMA GEMM: support = bf16(emb[uids]) @ bf16(W) ----------------
__global__ __launch_bounds__(256) void gemm_mfma(
    const int* __restrict__ uids, const float* __restrict__ emb,
    const unsigned short* __restrict__ Wt, unsigned short* __restrict__ support)
{
    __shared__ unsigned short As[128][40];
    __shared__ unsigned short Bs[128][40];

    const int t  = threadIdx.x;
    const int m0 = blockIdx.y * 128;
    const int n0 = blockIdx.x * 128;

    const int wave = t >> 6;
    const int lane = t & 63;
    const int wm   = (wave & 1) * 64;
    const int wn   = (wave >> 1) * 64;
    const int l16  = lane & 15;
    const int quad = lane >> 4;

    const int srow  = t >> 1;
    const int shalf = (t & 1) * 16;
    const int uid   = uids[m0 + srow];
    const float* arow = emb + (long)uid * EMBED + shalf;
    const unsigned short* brow = Wt + (long)(n0 + srow) * EMBED + shalf;

    f32x4 acc[4][4] = {};

    for (int k0 = 0; k0 < EMBED; k0 += 32) {
        const float4* ap = (const float4*)(arow + k0);
        float4 v0 = ap[0], v1 = ap[1], v2 = ap[2], v3 = ap[3];
        u32x4 lo, hi;
        lo.x = pk2(v0.x, v0.y); lo.y = pk2(v0.z, v0.w);
        lo.z = pk2(v1.x, v1.y); lo.w = pk2(v1.z, v1.w);
        hi.x = pk2(v2.x, v2.y); hi.y = pk2(v2.z, v2.w);
        hi.z = pk2(v3.x, v3.y); hi.w = pk2(v3.z, v3.w);
        *(u32x4*)&As[srow][shalf]     = lo;
        *(u32x4*)&As[srow][shalf + 8] = hi;
        const u32x4* bp = (const u32x4*)(brow + k0);
        *(u32x4*)&Bs[srow][shalf]     = bp[0];
        *(u32x4*)&Bs[srow][shalf + 8] = bp[1];
        __syncthreads();

        bf16x8 af[4], bfr[4];
#pragma unroll
        for (int i = 0; i < 4; ++i)
            af[i] = *(const bf16x8*)&As[wm + i * 16 + l16][quad * 8];
#pragma unroll
        for (int j = 0; j < 4; ++j)
            bfr[j] = *(const bf16x8*)&Bs[wn + j * 16 + l16][quad * 8];
#pragma unroll
        for (int i = 0; i < 4; ++i)
#pragma unroll
            for (int j = 0; j < 4; ++j)
                acc[i][j] = __builtin_amdgcn_mfma_f32_16x16x32_bf16(af[i], bfr[j], acc[i][j], 0, 0, 0);
        __syncthreads();
    }

#pragma unroll
    for (int i = 0; i < 4; ++i) {
#pragma unroll
        for (int j = 0; j < 4; ++j) {
            const int col = n0 + wn + j * 16 + l16;
#pragma unroll
            for (int r = 0; r < 4; ++r) {
                const int row = m0 + wm + i * 16 + quad * 4 + r;
                support[(long)row * EMBED + col] = f2bf(acc[i][j][r]);
            }
        }
    }
}

// ---------------- CSR build ----------------
__global__ void hist_kernel(const int* __restrict__ adj_row, int* __restrict__ counts) {
    int i = blockIdx.x * blockDim.x + threadIdx.x;
    if (i < NNZ_TOT) atomicAdd(&counts[adj_row[i]], 1);
}

__global__ __launch_bounds__(1024) void scan_kernel(
    const int* __restrict__ counts, int* __restrict__ row_start)
{
    __shared__ int ssum[1024];
    const int t = threadIdx.x;
    const int base = t * 32;
    int loc[32];
    int run = 0;
#pragma unroll
    for (int i = 0; i < 32; ++i) {
        int c = counts[base + i];
        loc[i] = run;
        run += c;
    }
    ssum[t] = run;
    __syncthreads();
    for (int off = 1; off < 1024; off <<= 1) {
        int v = (t >= off) ? ssum[t - off] : 0;
        __syncthreads();
        ssum[t] += v;
        __syncthreads();
    }
    int prefix = (t > 0) ? ssum[t - 1] : 0;
#pragma unroll
    for (int i = 0; i < 32; ++i) row_start[base + i] = prefix + loc[i];
    if (t == 1023) row_start[N_NODES] = ssum[1023];
}

__global__ void scatter_kernel(
    const int* __restrict__ adj_row, const int* __restrict__ adj_col,
    const float* __restrict__ adj_vals, const int* __restrict__ row_start,
    int* __restrict__ cursor, int2* __restrict__ sc)
{
    int i = blockIdx.x * blockDim.x + threadIdx.x;
    if (i < NNZ_TOT) {
        int r = adj_row[i];
        int pos = atomicAdd(&cursor[r], 1);
        sc[row_start[r] + pos] = make_int2(adj_col[i], __float_as_int(adj_vals[i]));
    }
}

// ---------------- aggregation v2: wave-per-edge-subset, 16B/lane gathers ----------------
__global__ __launch_bounds__(256) void agg_ln_v2(
    const int* __restrict__ row_start, const int2* __restrict__ sc,
    const unsigned short* __restrict__ support,
    const float* __restrict__ bias, const float* __restrict__ gamma,
    const float* __restrict__ beta, float* __restrict__ out)
{
    const int n = blockIdx.x;
    const int t = threadIdx.x;
    const int w = t >> 6;            // wave 0..3
    const int l = t & 63;            // lane: owns dims [8l, 8l+8)
    const int s = row_start[n];
    const int e = row_start[n + 1];

    const unsigned short* supp_l = support + l * 8;

    float acc[8] = {};
    int i = s + w;
    for (; i + 4 < e; i += 8) {
        int2 p0 = sc[i];
        int2 p1 = sc[i + 4];
        u32x4 u0 = *(const u32x4*)(supp_l + p0.x * EMBED);
        u32x4 u1 = *(const u32x4*)(supp_l + p1.x * EMBED);
        float v0 = __int_as_float(p0.y);
        float v1 = __int_as_float(p1.y);
#pragma unroll
        for (int j = 0; j < 4; ++j) {
            unsigned int a = u0[j];
            acc[2 * j]     = fmaf(v0, __uint_as_float(a << 16), acc[2 * j]);
            acc[2 * j + 1] = fmaf(v0, __uint_as_float(a & 0xffff0000u), acc[2 * j + 1]);
        }
#pragma unroll
        for (int j = 0; j < 4; ++j) {
            unsigned int a = u1[j];
            acc[2 * j]     = fmaf(v1, __uint_as_float(a << 16), acc[2 * j]);
            acc[2 * j + 1] = fmaf(v1, __uint_as_float(a & 0xffff0000u), acc[2 * j + 1]);
        }
    }
    if (i < e) {
        int2 p0 = sc[i];
        u32x4 u0 = *(const u32x4*)(supp_l + p0.x * EMBED);
        float v0 = __int_as_float(p0.y);
#pragma unroll
        for (int j = 0; j < 4; ++j) {
            unsigned int a = u0[j];
            acc[2 * j]     = fmaf(v0, __uint_as_float(a << 16), acc[2 * j]);
            acc[2 * j + 1] = fmaf(v0, __uint_as_float(a & 0xffff0000u), acc[2 * j + 1]);
        }
    }

    // combine 4 wave-partials via LDS
    __shared__ float part[4][EMBED];
    *(f32x4*)&part[w][l * 8]     = *(f32x4*)&acc[0];
    *(f32x4*)&part[w][l * 8 + 4] = *(f32x4*)&acc[4];
    __syncthreads();

    const int d = t * 2;   // thread owns dims d, d+1
    float x0 = part[0][d] + part[1][d] + part[2][d] + part[3][d] + bias[d];
    float x1 = part[0][d + 1] + part[1][d + 1] + part[2][d + 1] + part[3][d + 1] + bias[d + 1];

    float s1 = x0 + x1;
    float s2 = x0 * x0 + x1 * x1;
#pragma unroll
    for (int off = 32; off > 0; off >>= 1) {
        s1 += __shfl_down(s1, off, 64);
        s2 += __shfl_down(s2, off, 64);
    }
    __shared__ float ws1[4], ws2[4];
    const int wid = t >> 6, lane = t & 63;
    if (lane == 0) { ws1[wid] = s1; ws2[wid] = s2; }
    __syncthreads();
    if (t == 0) {
        ws1[0] = ws1[0] + ws1[1] + ws1[2] + ws1[3];
        ws2[0] = ws2[0] + ws2[1] + ws2[2] + ws2[3];
    }
    __syncthreads();
    const float mean = ws1[0] * (1.f / 512.f);
    const float var  = ws2[0] * (1.f / 512.f) - mean * mean;
    const float rstd = rsqrtf(var + LN_EPS);

    float2 o;
    o.x = (x0 - mean) * rstd * gamma[d] + beta[d];
    o.y = (x1 - mean) * rstd * gamma[d + 1] + beta[d + 1];
    *(float2*)&out[(long)n * EMBED + d] = o;
}

// ---------------- launch ----------------
extern "C" void kernel_launch(void* const* d_in, const int* in_sizes, int n_in,
                              void* d_out, int out_size, void* d_ws, size_t ws_size,
                              hipStream_t stream)
{
    const int*   user_ids = (const int*)  d_in[0];
    const int*   adj_row  = (const int*)  d_in[1];
    const int*   adj_col  = (const int*)  d_in[2];
    const float* adj_vals = (const float*)d_in[3];
    const float* emb      = (const float*)d_in[4];
    const float* W        = (const float*)d_in[5];
    const float* bias     = (const float*)d_in[6];
    const float* gamma    = (const float*)d_in[7];
    const float* beta     = (const float*)d_in[8];
    float* out = (float*)d_out;

    char* ws = (char*)d_ws;
    size_t off = 0;
    unsigned short* support = (unsigned short*)(ws + off); off += (size_t)N_NODES * EMBED * 2; // 32 MB
    unsigned short* Wt      = (unsigned short*)(ws + off); off += (size_t)EMBED * EMBED * 2;   // 512 KB
    int2*  sc        = (int2*) (ws + off); off += (size_t)NNZ_TOT * 8;                         // 8 MB
    int*   row_start = (int*)  (ws + off); off += (size_t)(N_NODES + 4) * 4;
    int*   counts    = (int*)  (ws + off); off += (size_t)N_NODES * 4;
    int*   cursor    = (int*)  (ws + off); off += (size_t)N_NODES * 4;   // contiguous with counts
    (void)off; (void)ws_size; (void)in_sizes; (void)n_in; (void)out_size;

    zero_ints<<<(2 * N_NODES + 255) / 256, 256, 0, stream>>>(counts, 2 * N_NODES);

    wt_kernel<<<dim3(16, 16), 256, 0, stream>>>(W, Wt);

    gemm_mfma<<<dim3(EMBED / 128, N_NODES / 128), 256, 0, stream>>>(user_ids, emb, Wt, support);

    hist_kernel<<<NNZ_TOT / 256, 256, 0, stream>>>(adj_row, counts);
    scan_kernel<<<1, 1024, 0, stream>>>(counts, row_start);
    scatter_kernel<<<NNZ_TOT / 256, 256, 0, stream>>>(adj_row, adj_col, adj_vals,
                                                      row_start, cursor, sc);

    agg_ln_v2<<<N_NODES, 256, 0, stream>>>(row_start, sc, support,
                                           bias, gamma, beta, out);
}